// Round 1
// baseline (2512.790 us; speedup 1.0000x reference)
//
#include <hip/hip_runtime.h>

typedef unsigned short u16;
typedef unsigned int u32;
using f32x4 = __attribute__((ext_vector_type(4))) float;
using s16x8 = __attribute__((ext_vector_type(8))) short;
using u16x4 = __attribute__((ext_vector_type(4))) u16;

#define DEV __device__ __forceinline__

DEV float bf2f(u16 u) { union { u32 i; float f; } v; v.i = ((u32)u) << 16; return v.f; }
DEV u16 f2bf(float f) {
  union { float ff; u32 uu; } v; v.ff = f;
  u32 r = (v.uu + 0x7fffu + ((v.uu >> 16) & 1u)) >> 16;
  return (u16)r;
}

DEV void gl_lds16(const void* g, void* l) {
  __builtin_amdgcn_global_load_lds(
      (const __attribute__((address_space(1))) u32*)g,
      (__attribute__((address_space(3))) u32*)l, 16, 0, 0);
}

// ---------------- L2 normalize per frame, emit bf16 ----------------
__global__ __launch_bounds__(256) void k_l2norm(const float* __restrict__ x, u16* __restrict__ xn) {
  int r = blockIdx.x, t = threadIdx.x;
  const float* xr = x + (size_t)r * 2048;
  float v[8], s = 0.f;
#pragma unroll
  for (int i = 0; i < 8; i++) { v[i] = xr[t + i*256]; s += v[i]*v[i]; }
#pragma unroll
  for (int off = 32; off > 0; off >>= 1) s += __shfl_xor(s, off, 64);
  __shared__ float red[4];
  if ((t & 63) == 0) red[t >> 6] = s;
  __syncthreads();
  float inv = 1.f / fmaxf(sqrtf(red[0]+red[1]+red[2]+red[3]), 1e-12f);
  u16* xo = xn + (size_t)r * 2048;
#pragma unroll
  for (int i = 0; i < 8; i++) xo[t + i*256] = f2bf(v[i]*inv);
}

// ---------------- f32 -> bf16 ----------------
__global__ void k_cvt(const float* __restrict__ in, u16* __restrict__ out, int n4) {
  int i = blockIdx.x*256 + threadIdx.x, st = gridDim.x*256;
  for (; i < n4; i += st) {
    f32x4 v = ((const f32x4*)in)[i];
    u16x4 o;
    o[0] = f2bf(v[0]); o[1] = f2bf(v[1]); o[2] = f2bf(v[2]); o[3] = f2bf(v[3]);
    ((u16x4*)out)[i] = o;
  }
}

// ---------------- c1 [4096][512] -> c1t bf16 [512][4096] ----------------
__global__ __launch_bounds__(256) void k_transpose(const float* __restrict__ c1, u16* __restrict__ c1t) {
  __shared__ float tile[32][33];
  int k0 = blockIdx.x*32, n0 = blockIdx.y*32;
  int tx = threadIdx.x & 31, ty = threadIdx.x >> 5;
  for (int i = ty; i < 32; i += 8) tile[i][tx] = c1[(size_t)(k0+i)*512 + n0 + tx];
  __syncthreads();
  for (int i = ty; i < 32; i += 8) c1t[(size_t)(n0+i)*4096 + k0 + tx] = f2bf(tile[tx][i]);
}

// ---------------- bf16 MFMA NT GEMM: C[m,n] = sum_k A[m,k]*Bt[n,k] (+bias) ----------------
// 128x128 tile, BK=32, 4 waves (2x2 of 64x64), m97-style global_load_lds staging.
template<bool WF32, bool WBF16>
__global__ __launch_bounds__(256) void k_gemm(
    const u16* __restrict__ A, const u16* __restrict__ Bt, const float* __restrict__ bias,
    float* __restrict__ Cf, u16* __restrict__ Cb, int N, int K) {
  __shared__ u16 As[128*32];
  __shared__ u16 Bs[128*32];
  int t = threadIdx.x, wv = t >> 6;
  int quad = (t & 63) >> 4, lr = t & 15;
  size_t m0 = (size_t)blockIdx.x * 128, n0 = (size_t)blockIdx.y * 128;
  int wm = wv & 1, wn = wv >> 1;
  int srow = t >> 2, scol = (t & 3) * 8;
  const u16* gA = A + (m0 + srow)*(size_t)K + scol;
  const u16* gB = Bt + (n0 + srow)*(size_t)K + scol;
  u16* lA = &As[wv*512];
  u16* lB = &Bs[wv*512];
  f32x4 acc[4][4];
#pragma unroll
  for (int i = 0; i < 4; i++)
#pragma unroll
    for (int j = 0; j < 4; j++) acc[i][j] = (f32x4){0.f,0.f,0.f,0.f};
  for (int k0 = 0; k0 < K; k0 += 32) {
    gl_lds16(gA + k0, lA);
    gl_lds16(gA + (size_t)64*K + k0, lA + 2048);
    gl_lds16(gB + k0, lB);
    gl_lds16(gB + (size_t)64*K + k0, lB + 2048);
    __syncthreads();   // vmcnt drain + barrier
    s16x8 af[4], bfr[4];
#pragma unroll
    for (int i = 0; i < 4; i++) {
      af[i]  = *(const s16x8*)&As[(wm*64 + i*16 + lr)*32 + quad*8];
      bfr[i] = *(const s16x8*)&Bs[(wn*64 + i*16 + lr)*32 + quad*8];
    }
#pragma unroll
    for (int i = 0; i < 4; i++)
#pragma unroll
      for (int j = 0; j < 4; j++)
        acc[i][j] = __builtin_amdgcn_mfma_f32_16x16x32_bf16(af[i], bfr[j], acc[i][j], 0, 0, 0);
    __syncthreads();
  }
#pragma unroll
  for (int j = 0; j < 4; j++) {
    size_t nn = n0 + wn*64 + j*16 + lr;
    float bj = bias ? bias[nn] : 0.f;
#pragma unroll
    for (int i = 0; i < 4; i++) {
      size_t mr = m0 + wm*64 + i*16 + quad*4;
#pragma unroll
      for (int r = 0; r < 4; r++) {
        float v = acc[i][j][r] + bj;
        if (WF32)  Cf[(mr + r)*N + nn] = v;
        if (WBF16) Cb[(mr + r)*N + nn] = f2bf(v);
      }
    }
  }
}

// ---------------- attention: att[m,o] = sigmoid(h[m,:] . fc2_w[o,:] + b) ----------------
__global__ __launch_bounds__(256) void k_att(const u16* __restrict__ hb, const float* __restrict__ w2,
                                             const float* __restrict__ b2, float* __restrict__ att) {
  int m = blockIdx.x, t = threadIdx.x;
  int o = t >> 5, j = t & 31;
  const u16* hr = hb + (size_t)m * 4096;
  const float* wr = w2 + (size_t)o * 4096;
  float acc = 0.f;
  for (int k = j; k < 4096; k += 32) acc += bf2f(hr[k]) * wr[k];
#pragma unroll
  for (int off = 16; off > 0; off >>= 1) acc += __shfl_xor(acc, off, 64);
  if (j == 0) att[m*8 + o] = 1.f / (1.f + __expf(-(acc + b2[o])));
}

// ---------------- bn1 + softmax(K=64) + att, in place on act [9600][512] ----------------
__global__ __launch_bounds__(512) void k_softmax(float* __restrict__ act, const float* __restrict__ att,
    const float* __restrict__ g, const float* __restrict__ b,
    const float* __restrict__ mu, const float* __restrict__ var) {
  int m = blockIdx.x, t = threadIdx.x;
  int gi = t >> 6, ln = t & 63;
  int c = gi*64 + ln;
  size_t idx = (size_t)m*512 + c;
  float v = act[idx];
  v = (v - mu[c]) * rsqrtf(var[c] + 1e-5f) * g[c] + b[c];
  float mx = v;
#pragma unroll
  for (int off = 32; off > 0; off >>= 1) mx = fmaxf(mx, __shfl_xor(mx, off, 64));
  float e = __expf(v - mx);
  float s = e;
#pragma unroll
  for (int off = 32; off > 0; off >>= 1) s += __shfl_xor(s, off, 64);
  act[idx] = (e / s) * att[m*8 + gi];
}

// ---------------- a_sum[b,k] = sum_n act[b,n,k] ----------------
__global__ __launch_bounds__(256) void k_asum(const float* __restrict__ act, float* __restrict__ a_sum) {
  int b = blockIdx.x, s = blockIdx.y, t = threadIdx.x;
  int k = t & 63, ns = t >> 6;
  float acc = 0.f;
  int nbeg = s*300;
  for (int n = nbeg + ns; n < nbeg + 300; n += 4)
    acc += act[((size_t)b*2400 + n)*64 + k];
  __shared__ float red[4][64];
  red[ns][k] = acc;
  __syncthreads();
  if (t < 64) atomicAdd(&a_sum[b*64 + t], red[0][t]+red[1][t]+red[2][t]+red[3][t]);
}

// ---------------- vlad[b,f,k] = sum_n res[b,n,f]*act[b,n,k] ----------------
__global__ __launch_bounds__(256) void k_vlad(const u16* __restrict__ hb, const float* __restrict__ act,
                                              float* __restrict__ vlad) {
  int fx = blockIdx.x, b = blockIdx.y, t = threadIdx.x;
  int tf = t >> 4, tk = t & 15;
  __shared__ float Rs[16][64];
  __shared__ float Ss[16][64];
  float acc[4][4] = {};
  size_t baseR = ((size_t)b*2400)*512 + (size_t)fx*64;
  size_t baseS = ((size_t)b*2400)*64;
  int sr = t >> 4, sc = (t & 15)*4;
  for (int n0 = 0; n0 < 2400; n0 += 16) {
    u16x4 rv = *(const u16x4*)&hb[baseR + (size_t)(n0+sr)*512 + sc];
    f32x4 sv = *(const f32x4*)&act[baseS + (size_t)(n0+sr)*64 + sc];
    __syncthreads();
    Rs[sr][sc+0] = bf2f(rv[0]); Rs[sr][sc+1] = bf2f(rv[1]);
    Rs[sr][sc+2] = bf2f(rv[2]); Rs[sr][sc+3] = bf2f(rv[3]);
    *(f32x4*)&Ss[sr][sc] = sv;
    __syncthreads();
#pragma unroll
    for (int nn = 0; nn < 16; nn++) {
      f32x4 r4 = *(const f32x4*)&Rs[nn][tf*4];
      f32x4 s4 = *(const f32x4*)&Ss[nn][tk*4];
#pragma unroll
      for (int a = 0; a < 4; a++)
#pragma unroll
        for (int c = 0; c < 4; c++) acc[a][c] += r4[a]*s4[c];
    }
  }
#pragma unroll
  for (int a = 0; a < 4; a++) {
    f32x4 o = {acc[a][0], acc[a][1], acc[a][2], acc[a][3]};
    *(f32x4*)&vlad[((size_t)b*512 + fx*64 + tf*4 + a)*64 + tk*4] = o;
  }
}

// ---------------- subtract a, intra-norm over f, bn2 -> vladn [32][32768] ----------------
__global__ __launch_bounds__(256) void k_norm2(const float* __restrict__ vlad, const float* __restrict__ a_sum,
    const float* __restrict__ c2, const float* __restrict__ g, const float* __restrict__ b,
    const float* __restrict__ mu, const float* __restrict__ var, float* __restrict__ out) {
  int k = blockIdx.x, bb = blockIdx.y, t = threadIdx.x;
  float as = a_sum[bb*64 + k];
  int f0 = t, f1 = t + 256;
  size_t base = (size_t)bb*512*64;
  float x0 = vlad[base + (size_t)f0*64 + k] - as * c2[f0*64 + k];
  float x1 = vlad[base + (size_t)f1*64 + k] - as * c2[f1*64 + k];
  float s = x0*x0 + x1*x1;
#pragma unroll
  for (int off = 32; off > 0; off >>= 1) s += __shfl_xor(s, off, 64);
  __shared__ float red[4];
  if ((t & 63) == 0) red[t >> 6] = s;
  __syncthreads();
  float inv = 1.f / fmaxf(sqrtf(red[0]+red[1]+red[2]+red[3]), 1e-12f);
  int c0 = f0*64 + k, c1 = f1*64 + k;
  out[(size_t)bb*32768 + c0] = (x0*inv - mu[c0]) * rsqrtf(var[c0]+1e-5f) * g[c0] + b[c0];
  out[(size_t)bb*32768 + c1] = (x1*inv - mu[c1]) * rsqrtf(var[c1]+1e-5f) * g[c1] + b[c1];
}

// ---------------- small-M (M=32) fp32 GEMM, C[m,n]=epi(sum_k A[m,k]W[n,k]+bias) ----------------
// 8 n per block (4 pairs x 64 threads); A chunk staged in LDS; EPI: 0 none,1 BN,2 BN+relu,3 sigmoid
template<int EPI>
__global__ __launch_bounds__(256) void k_smallm(const float* __restrict__ A, const float* __restrict__ W,
    const float* __restrict__ bias, const float* __restrict__ bg, const float* __restrict__ bb,
    const float* __restrict__ bm, const float* __restrict__ bv, float* __restrict__ C, int N, int K) {
  __shared__ float As[32*256];
  __shared__ float red[8][33];
  int t = threadIdx.x, p = t >> 6, tg = t & 63;
  int n0 = blockIdx.x*8 + p*2;
  bool ok0 = n0 < N, ok1 = (n0+1) < N;
  const float* w0 = W + (size_t)(ok0 ? n0 : 0) * K;
  const float* w1 = W + (size_t)(ok1 ? n0+1 : 0) * K;
  float a0[32], a1[32];
#pragma unroll
  for (int m = 0; m < 32; m++) { a0[m] = 0.f; a1[m] = 0.f; }
  for (int kc = 0; kc < K; kc += 256) {
    __syncthreads();
    for (int idx = t; idx < 8192; idx += 256)
      As[idx] = A[(size_t)(idx >> 8)*K + kc + (idx & 255)];
    __syncthreads();
#pragma unroll
    for (int kk0 = 0; kk0 < 256; kk0 += 64) {
      int kk = kk0 + tg;
      float wa = ok0 ? w0[kc + kk] : 0.f;
      float wb = ok1 ? w1[kc + kk] : 0.f;
#pragma unroll
      for (int m = 0; m < 32; m++) {
        float a = As[m*256 + kk];
        a0[m] += a*wa; a1[m] += a*wb;
      }
    }
  }
#pragma unroll
  for (int m = 0; m < 32; m++) {
    float v0 = a0[m], v1 = a1[m];
#pragma unroll
    for (int off = 32; off > 0; off >>= 1) { v0 += __shfl_xor(v0, off, 64); v1 += __shfl_xor(v1, off, 64); }
    if (tg == 0) { red[p*2][m] = v0; red[p*2+1][m] = v1; }
  }
  __syncthreads();
  {
    int nl = t >> 5, m = t & 31;
    int n = blockIdx.x*8 + nl;
    if (n < N) {
      float v = red[nl][m] + (bias ? bias[n] : 0.f);
      if (EPI == 1 || EPI == 2) {
        v = (v - bm[n]) * rsqrtf(bv[n] + 1e-5f) * bg[n] + bb[n];
        if (EPI == 2) v = fmaxf(v, 0.f);
      } else if (EPI == 3) {
        v = 1.f / (1.f + __expf(-v));
      }
      C[(size_t)m*N + n] = v;
    }
  }
}

// ---------------- elementwise multiply ----------------
__global__ void k_mul(const float* __restrict__ a, const float* __restrict__ b, float* __restrict__ o, int n) {
  int i = blockIdx.x*256 + threadIdx.x;
  if (i < n) o[i] = a[i]*b[i];
}

extern "C" void kernel_launch(void* const* d_in, const int* in_sizes, int n_in,
                              void* d_out, int out_size, void* d_ws, size_t ws_size,
                              hipStream_t stream) {
  (void)in_sizes; (void)n_in; (void)out_size; (void)ws_size;
  const float* x      = (const float*)d_in[0];
  const float* fc1_w  = (const float*)d_in[1];
  const float* fc1_b  = (const float*)d_in[2];
  const float* fc2_w  = (const float*)d_in[3];
  const float* fc2_b  = (const float*)d_in[4];
  const float* c1     = (const float*)d_in[5];
  const float* c2     = (const float*)d_in[6];
  const float* bn1_g  = (const float*)d_in[7];
  const float* bn1_b  = (const float*)d_in[8];
  const float* bn1_m  = (const float*)d_in[9];
  const float* bn1_v  = (const float*)d_in[10];
  const float* bn2_g  = (const float*)d_in[11];
  const float* bn2_b  = (const float*)d_in[12];
  const float* bn2_m  = (const float*)d_in[13];
  const float* bn2_v  = (const float*)d_in[14];
  const float* cgf_w  = (const float*)d_in[15];
  const float* cgf_b  = (const float*)d_in[16];
  const float* cgbn_g = (const float*)d_in[17];
  const float* cgbn_b = (const float*)d_in[18];
  const float* cgbn_m = (const float*)d_in[19];
  const float* cgbn_v = (const float*)d_in[20];
  const float* g1_w   = (const float*)d_in[21];
  const float* g1_b   = (const float*)d_in[22];
  const float* gbn_g  = (const float*)d_in[23];
  const float* gbn_b  = (const float*)d_in[24];
  const float* gbn_m  = (const float*)d_in[25];
  const float* gbn_v  = (const float*)d_in[26];
  const float* g2_w   = (const float*)d_in[27];
  const float* g2_b   = (const float*)d_in[28];
  const float* fc3_w  = (const float*)d_in[29];
  const float* fc3_b  = (const float*)d_in[30];

  char* w = (char*)d_ws;
  u16*   xn    = (u16*)  (w + 0);
  u16*   w1b   = (u16*)  (w + 39321600);
  u16*   c1t   = (u16*)  (w + 56098816);
  u16*   hb    = (u16*)  (w + 60293120);
  float* att   = (float*)(w + 138936320);
  float* act   = (float*)(w + 139243520);
  float* a_sum = (float*)(w + 158904320);
  float* vlad  = (float*)(w + 158912512);
  float* vladn = (float*)(w + 163106816);
  float* y     = (float*)(w + 167301120);
  float* z     = (float*)(w + 167563264);
  float* gate  = (float*)(w + 167596032);
  float* yg    = (float*)(w + 167858176);
  // total workspace use: 168,120,320 bytes

  hipMemsetAsync(a_sum, 0, 32*64*sizeof(float), stream);
  k_l2norm<<<9600, 256, 0, stream>>>(x, xn);
  k_cvt<<<2048, 256, 0, stream>>>(fc1_w, w1b, (4096*2048)/4);
  k_transpose<<<dim3(128, 16), 256, 0, stream>>>(c1, c1t);
  // GEMM1: h = xn @ fc1_w.T + fc1_b  -> bf16 [9600][4096]
  k_gemm<false, true><<<dim3(75, 32), 256, 0, stream>>>(xn, w1b, fc1_b, nullptr, hb, 4096, 2048);
  k_att<<<9600, 256, 0, stream>>>(hb, fc2_w, fc2_b, att);
  // GEMM2: act = h @ c1 -> f32 [9600][512]
  k_gemm<true, false><<<dim3(75, 4), 256, 0, stream>>>(hb, c1t, nullptr, act, nullptr, 512, 4096);
  k_softmax<<<9600, 512, 0, stream>>>(act, att, bn1_g, bn1_b, bn1_m, bn1_v);
  k_asum<<<dim3(32, 8), 256, 0, stream>>>(act, a_sum);
  k_vlad<<<dim3(8, 32), 256, 0, stream>>>(hb, act, vlad);
  k_norm2<<<dim3(64, 32), 256, 0, stream>>>(vlad, a_sum, c2, bn2_g, bn2_b, bn2_m, bn2_v, vladn);
  k_smallm<1><<<256, 256, 0, stream>>>(vladn, cgf_w, cgf_b, cgbn_g, cgbn_b, cgbn_m, cgbn_v, y, 2048, 32768);
  k_smallm<2><<<32, 256, 0, stream>>>(y, g1_w, g1_b, gbn_g, gbn_b, gbn_m, gbn_v, z, 256, 2048);
  k_smallm<3><<<256, 256, 0, stream>>>(z, g2_w, g2_b, nullptr, nullptr, nullptr, nullptr, gate, 2048, 256);
  k_mul<<<256, 256, 0, stream>>>(y, gate, yg, 65536);
  k_smallm<0><<<483, 256, 0, stream>>>(yg, fc3_w, fc3_b, nullptr, nullptr, nullptr, nullptr, (float*)d_out, 3862, 2048);
}

// Round 2
// 1261.222 us; speedup vs baseline: 1.9923x; 1.9923x over previous
//
#include <hip/hip_runtime.h>

typedef unsigned short u16;
typedef unsigned int u32;
using f32x4 = __attribute__((ext_vector_type(4))) float;
using s16x8 = __attribute__((ext_vector_type(8))) short;
using u16x4 = __attribute__((ext_vector_type(4))) u16;

#define DEV __device__ __forceinline__

DEV float bf2f(u16 u) { union { u32 i; float f; } v; v.i = ((u32)u) << 16; return v.f; }
DEV u16 f2bf(float f) {
  union { float ff; u32 uu; } v; v.ff = f;
  u32 r = (v.uu + 0x7fffu + ((v.uu >> 16) & 1u)) >> 16;
  return (u16)r;
}

DEV void gl_lds16(const void* g, void* l) {
  __builtin_amdgcn_global_load_lds(
      (const __attribute__((address_space(1))) u32*)g,
      (__attribute__((address_space(3))) u32*)l, 16, 0, 0);
}

// ---------------- L2 normalize per frame, emit bf16 ----------------
__global__ __launch_bounds__(256) void k_l2norm(const float* __restrict__ x, u16* __restrict__ xn) {
  int r = blockIdx.x, t = threadIdx.x;
  const float* xr = x + (size_t)r * 2048;
  float v[8], s = 0.f;
#pragma unroll
  for (int i = 0; i < 8; i++) { v[i] = xr[t + i*256]; s += v[i]*v[i]; }
#pragma unroll
  for (int off = 32; off > 0; off >>= 1) s += __shfl_xor(s, off, 64);
  __shared__ float red[4];
  if ((t & 63) == 0) red[t >> 6] = s;
  __syncthreads();
  float inv = 1.f / fmaxf(sqrtf(red[0]+red[1]+red[2]+red[3]), 1e-12f);
  u16* xo = xn + (size_t)r * 2048;
#pragma unroll
  for (int i = 0; i < 8; i++) xo[t + i*256] = f2bf(v[i]*inv);
}

// ---------------- f32 -> bf16 ----------------
__global__ void k_cvt(const float* __restrict__ in, u16* __restrict__ out, int n4) {
  int i = blockIdx.x*256 + threadIdx.x, st = gridDim.x*256;
  for (; i < n4; i += st) {
    f32x4 v = ((const f32x4*)in)[i];
    u16x4 o;
    o[0] = f2bf(v[0]); o[1] = f2bf(v[1]); o[2] = f2bf(v[2]); o[3] = f2bf(v[3]);
    ((u16x4*)out)[i] = o;
  }
}

// ---------------- c1 [4096][512] -> c1t bf16 [512][4096] ----------------
__global__ __launch_bounds__(256) void k_transpose(const float* __restrict__ c1, u16* __restrict__ c1t) {
  __shared__ float tile[32][33];
  int k0 = blockIdx.x*32, n0 = blockIdx.y*32;
  int tx = threadIdx.x & 31, ty = threadIdx.x >> 5;
  for (int i = ty; i < 32; i += 8) tile[i][tx] = c1[(size_t)(k0+i)*512 + n0 + tx];
  __syncthreads();
  for (int i = ty; i < 32; i += 8) c1t[(size_t)(n0+i)*4096 + k0 + tx] = f2bf(tile[tx][i]);
}

// ---------------- bf16 MFMA NT GEMM: C[m,n] = sum_k A[m,k]*Bt[n,k] (+bias) ----------------
template<bool WF32, bool WBF16>
__global__ __launch_bounds__(256) void k_gemm(
    const u16* __restrict__ A, const u16* __restrict__ Bt, const float* __restrict__ bias,
    float* __restrict__ Cf, u16* __restrict__ Cb, int N, int K) {
  __shared__ u16 As[128*32];
  __shared__ u16 Bs[128*32];
  int t = threadIdx.x, wv = t >> 6;
  int quad = (t & 63) >> 4, lr = t & 15;
  size_t m0 = (size_t)blockIdx.x * 128, n0 = (size_t)blockIdx.y * 128;
  int wm = wv & 1, wn = wv >> 1;
  int srow = t >> 2, scol = (t & 3) * 8;
  const u16* gA = A + (m0 + srow)*(size_t)K + scol;
  const u16* gB = Bt + (n0 + srow)*(size_t)K + scol;
  u16* lA = &As[wv*512];
  u16* lB = &Bs[wv*512];
  f32x4 acc[4][4];
#pragma unroll
  for (int i = 0; i < 4; i++)
#pragma unroll
    for (int j = 0; j < 4; j++) acc[i][j] = (f32x4){0.f,0.f,0.f,0.f};
  for (int k0 = 0; k0 < K; k0 += 32) {
    gl_lds16(gA + k0, lA);
    gl_lds16(gA + (size_t)64*K + k0, lA + 2048);
    gl_lds16(gB + k0, lB);
    gl_lds16(gB + (size_t)64*K + k0, lB + 2048);
    __syncthreads();
    s16x8 af[4], bfr[4];
#pragma unroll
    for (int i = 0; i < 4; i++) {
      af[i]  = *(const s16x8*)&As[(wm*64 + i*16 + lr)*32 + quad*8];
      bfr[i] = *(const s16x8*)&Bs[(wn*64 + i*16 + lr)*32 + quad*8];
    }
#pragma unroll
    for (int i = 0; i < 4; i++)
#pragma unroll
      for (int j = 0; j < 4; j++)
        acc[i][j] = __builtin_amdgcn_mfma_f32_16x16x32_bf16(af[i], bfr[j], acc[i][j], 0, 0, 0);
    __syncthreads();
  }
#pragma unroll
  for (int j = 0; j < 4; j++) {
    size_t nn = n0 + wn*64 + j*16 + lr;
    float bj = bias ? bias[nn] : 0.f;
#pragma unroll
    for (int i = 0; i < 4; i++) {
      size_t mr = m0 + wm*64 + i*16 + quad*4;
#pragma unroll
      for (int r = 0; r < 4; r++) {
        float v = acc[i][j][r] + bj;
        if (WF32)  Cf[(mr + r)*N + nn] = v;
        if (WBF16) Cb[(mr + r)*N + nn] = f2bf(v);
      }
    }
  }
}

// ---------------- split-K small-M MFMA GEMM ----------------
// P[ks][32][Npad] partial = A[32][K] chunk . W[N][K]^T chunk, fp32 in, bf16 MFMA.
// Block: 256 thr, tile 32x128, BK=64; grid (Npad/128, KSPLIT); KC = K/KSPLIT.
__global__ __launch_bounds__(256) void k_skgemm(
    const float* __restrict__ A, const float* __restrict__ W,
    float* __restrict__ P, int N, int K, int KC, int Npad) {
  constexpr int LDB = 72;                 // u16 stride, breaks bank alias
  __shared__ u16 Bs[128*LDB];
  __shared__ u16 As[32*LDB];
  int t = threadIdx.x;
  int wv = t >> 6, quad = (t & 63) >> 4, lr = t & 15;
  int n0 = blockIdx.x * 128;
  size_t kc0 = (size_t)blockIdx.y * KC;
  f32x4 acc[2][2];
#pragma unroll
  for (int i = 0; i < 2; i++)
#pragma unroll
    for (int j = 0; j < 2; j++) acc[i][j] = (f32x4){0.f,0.f,0.f,0.f};
  int wl[8]; size_t wg[8];
#pragma unroll
  for (int i = 0; i < 8; i++) {
    int slot = i*256 + t;
    int r = slot >> 4, q = slot & 15;
    int row = n0 + r; if (row >= N) row = N - 1;
    wl[i] = r*LDB + q*4;
    wg[i] = (size_t)row*K + kc0 + q*4;
  }
  int al[2]; size_t ag[2];
#pragma unroll
  for (int i = 0; i < 2; i++) {
    int slot = i*256 + t;
    int r = slot >> 4, q = slot & 15;
    al[i] = r*LDB + q*4;
    ag[i] = (size_t)r*K + kc0 + q*4;
  }
  int nst = KC >> 6;
  f32x4 wv4[8], av4[2];
#pragma unroll
  for (int i = 0; i < 8; i++) wv4[i] = *(const f32x4*)(W + wg[i]);
#pragma unroll
  for (int i = 0; i < 2; i++) av4[i] = *(const f32x4*)(A + ag[i]);
  for (int s = 0; s < nst; s++) {
    if (s) __syncthreads();               // prior frag reads done before overwrite
#pragma unroll
    for (int i = 0; i < 8; i++) {
      u16x4 o;
      o[0] = f2bf(wv4[i][0]); o[1] = f2bf(wv4[i][1]);
      o[2] = f2bf(wv4[i][2]); o[3] = f2bf(wv4[i][3]);
      *(u16x4*)&Bs[wl[i]] = o;
    }
#pragma unroll
    for (int i = 0; i < 2; i++) {
      u16x4 o;
      o[0] = f2bf(av4[i][0]); o[1] = f2bf(av4[i][1]);
      o[2] = f2bf(av4[i][2]); o[3] = f2bf(av4[i][3]);
      *(u16x4*)&As[al[i]] = o;
    }
    __syncthreads();
    if (s + 1 < nst) {                    // prefetch next stage, overlap MFMA
      int off = (s + 1) * 64;
#pragma unroll
      for (int i = 0; i < 8; i++) wv4[i] = *(const f32x4*)(W + wg[i] + off);
#pragma unroll
      for (int i = 0; i < 2; i++) av4[i] = *(const f32x4*)(A + ag[i] + off);
    }
#pragma unroll
    for (int ks = 0; ks < 2; ks++) {
      s16x8 af[2];
#pragma unroll
      for (int i = 0; i < 2; i++)
        af[i] = *(const s16x8*)&As[(i*16 + lr)*LDB + ks*32 + quad*8];
#pragma unroll
      for (int j = 0; j < 2; j++) {
        s16x8 bf = *(const s16x8*)&Bs[(wv*32 + j*16 + lr)*LDB + ks*32 + quad*8];
#pragma unroll
        for (int i = 0; i < 2; i++)
          acc[i][j] = __builtin_amdgcn_mfma_f32_16x16x32_bf16(af[i], bf, acc[i][j], 0, 0, 0);
      }
    }
  }
#pragma unroll
  for (int i = 0; i < 2; i++)
#pragma unroll
    for (int j = 0; j < 2; j++) {
      int n = n0 + wv*32 + j*16 + lr;
#pragma unroll
      for (int r = 0; r < 4; r++) {
        int m = i*16 + quad*4 + r;
        P[((size_t)blockIdx.y*32 + m)*Npad + n] = acc[i][j][r];
      }
    }
}

// ---------------- split-K reduce + epilogue ----------------
// EPI: 0 bias, 1 BN, 2 BN+relu, 3 sigmoid
template<int EPI>
__global__ __launch_bounds__(256) void k_skred(const float* __restrict__ P, int KSPLIT, int N, int Npad,
    const float* __restrict__ bias, const float* __restrict__ bg, const float* __restrict__ bb,
    const float* __restrict__ bm, const float* __restrict__ bv, float* __restrict__ C) {
  int idx = blockIdx.x*256 + threadIdx.x;
  if (idx >= 32*N) return;
  int m = idx / N, n = idx - m*N;
  float s = 0.f;
  for (int k = 0; k < KSPLIT; k++) s += P[((size_t)k*32 + m)*Npad + n];
  float v = s + (bias ? bias[n] : 0.f);
  if (EPI == 1 || EPI == 2) {
    v = (v - bm[n]) * rsqrtf(bv[n] + 1e-5f) * bg[n] + bb[n];
    if (EPI == 2) v = fmaxf(v, 0.f);
  } else if (EPI == 3) {
    v = 1.f / (1.f + __expf(-v));
  }
  C[idx] = v;
}

// ---------------- attention: att[m,o] = sigmoid(h[m,:] . fc2_w[o,:] + b) ----------------
__global__ __launch_bounds__(256) void k_att(const u16* __restrict__ hb, const float* __restrict__ w2,
                                             const float* __restrict__ b2, float* __restrict__ att) {
  int m = blockIdx.x, t = threadIdx.x;
  int o = t >> 5, j = t & 31;
  const u16* hr = hb + (size_t)m * 4096;
  const float* wr = w2 + (size_t)o * 4096;
  float acc = 0.f;
  for (int k = j; k < 4096; k += 32) acc += bf2f(hr[k]) * wr[k];
#pragma unroll
  for (int off = 16; off > 0; off >>= 1) acc += __shfl_xor(acc, off, 64);
  if (j == 0) att[m*8 + o] = 1.f / (1.f + __expf(-(acc + b2[o])));
}

// ---------------- bn1 + softmax(K=64) + att, in place on act [9600][512] ----------------
__global__ __launch_bounds__(512) void k_softmax(float* __restrict__ act, const float* __restrict__ att,
    const float* __restrict__ g, const float* __restrict__ b,
    const float* __restrict__ mu, const float* __restrict__ var) {
  int m = blockIdx.x, t = threadIdx.x;
  int gi = t >> 6, ln = t & 63;
  int c = gi*64 + ln;
  size_t idx = (size_t)m*512 + c;
  float v = act[idx];
  v = (v - mu[c]) * rsqrtf(var[c] + 1e-5f) * g[c] + b[c];
  float mx = v;
#pragma unroll
  for (int off = 32; off > 0; off >>= 1) mx = fmaxf(mx, __shfl_xor(mx, off, 64));
  float e = __expf(v - mx);
  float s = e;
#pragma unroll
  for (int off = 32; off > 0; off >>= 1) s += __shfl_xor(s, off, 64);
  act[idx] = (e / s) * att[m*8 + gi];
}

// ---------------- a_sum[b,k] = sum_n act[b,n,k] ----------------
__global__ __launch_bounds__(256) void k_asum(const float* __restrict__ act, float* __restrict__ a_sum) {
  int b = blockIdx.x, s = blockIdx.y, t = threadIdx.x;
  int k = t & 63, ns = t >> 6;
  float acc = 0.f;
  int nbeg = s*300;
  for (int n = nbeg + ns; n < nbeg + 300; n += 4)
    acc += act[((size_t)b*2400 + n)*64 + k];
  __shared__ float red[4][64];
  red[ns][k] = acc;
  __syncthreads();
  if (t < 64) atomicAdd(&a_sum[b*64 + t], red[0][t]+red[1][t]+red[2][t]+red[3][t]);
}

// ---------------- vlad[b,f,k] = sum_n res[b,n,f]*act[b,n,k] ----------------
__global__ __launch_bounds__(256) void k_vlad(const u16* __restrict__ hb, const float* __restrict__ act,
                                              float* __restrict__ vlad) {
  int fx = blockIdx.x, b = blockIdx.y, t = threadIdx.x;
  int tf = t >> 4, tk = t & 15;
  __shared__ float Rs[16][64];
  __shared__ float Ss[16][64];
  float acc[4][4] = {};
  size_t baseR = ((size_t)b*2400)*512 + (size_t)fx*64;
  size_t baseS = ((size_t)b*2400)*64;
  int sr = t >> 4, sc = (t & 15)*4;
  for (int n0 = 0; n0 < 2400; n0 += 16) {
    u16x4 rv = *(const u16x4*)&hb[baseR + (size_t)(n0+sr)*512 + sc];
    f32x4 sv = *(const f32x4*)&act[baseS + (size_t)(n0+sr)*64 + sc];
    __syncthreads();
    Rs[sr][sc+0] = bf2f(rv[0]); Rs[sr][sc+1] = bf2f(rv[1]);
    Rs[sr][sc+2] = bf2f(rv[2]); Rs[sr][sc+3] = bf2f(rv[3]);
    *(f32x4*)&Ss[sr][sc] = sv;
    __syncthreads();
#pragma unroll
    for (int nn = 0; nn < 16; nn++) {
      f32x4 r4 = *(const f32x4*)&Rs[nn][tf*4];
      f32x4 s4 = *(const f32x4*)&Ss[nn][tk*4];
#pragma unroll
      for (int a = 0; a < 4; a++)
#pragma unroll
        for (int c = 0; c < 4; c++) acc[a][c] += r4[a]*s4[c];
    }
  }
#pragma unroll
  for (int a = 0; a < 4; a++) {
    f32x4 o = {acc[a][0], acc[a][1], acc[a][2], acc[a][3]};
    *(f32x4*)&vlad[((size_t)b*512 + fx*64 + tf*4 + a)*64 + tk*4] = o;
  }
}

// ---------------- subtract a, intra-norm over f, bn2 -> vladn [32][32768] ----------------
__global__ __launch_bounds__(256) void k_norm2(const float* __restrict__ vlad, const float* __restrict__ a_sum,
    const float* __restrict__ c2, const float* __restrict__ g, const float* __restrict__ b,
    const float* __restrict__ mu, const float* __restrict__ var, float* __restrict__ out) {
  int k = blockIdx.x, bb = blockIdx.y, t = threadIdx.x;
  float as = a_sum[bb*64 + k];
  int f0 = t, f1 = t + 256;
  size_t base = (size_t)bb*512*64;
  float x0 = vlad[base + (size_t)f0*64 + k] - as * c2[f0*64 + k];
  float x1 = vlad[base + (size_t)f1*64 + k] - as * c2[f1*64 + k];
  float s = x0*x0 + x1*x1;
#pragma unroll
  for (int off = 32; off > 0; off >>= 1) s += __shfl_xor(s, off, 64);
  __shared__ float red[4];
  if ((t & 63) == 0) red[t >> 6] = s;
  __syncthreads();
  float inv = 1.f / fmaxf(sqrtf(red[0]+red[1]+red[2]+red[3]), 1e-12f);
  int c0 = f0*64 + k, c1 = f1*64 + k;
  out[(size_t)bb*32768 + c0] = (x0*inv - mu[c0]) * rsqrtf(var[c0]+1e-5f) * g[c0] + b[c0];
  out[(size_t)bb*32768 + c1] = (x1*inv - mu[c1]) * rsqrtf(var[c1]+1e-5f) * g[c1] + b[c1];
}

// ---------------- elementwise multiply ----------------
__global__ void k_mul(const float* __restrict__ a, const float* __restrict__ b, float* __restrict__ o, int n) {
  int i = blockIdx.x*256 + threadIdx.x;
  if (i < n) o[i] = a[i]*b[i];
}

extern "C" void kernel_launch(void* const* d_in, const int* in_sizes, int n_in,
                              void* d_out, int out_size, void* d_ws, size_t ws_size,
                              hipStream_t stream) {
  (void)in_sizes; (void)n_in; (void)out_size; (void)ws_size;
  const float* x      = (const float*)d_in[0];
  const float* fc1_w  = (const float*)d_in[1];
  const float* fc1_b  = (const float*)d_in[2];
  const float* fc2_w  = (const float*)d_in[3];
  const float* fc2_b  = (const float*)d_in[4];
  const float* c1     = (const float*)d_in[5];
  const float* c2     = (const float*)d_in[6];
  const float* bn1_g  = (const float*)d_in[7];
  const float* bn1_b  = (const float*)d_in[8];
  const float* bn1_m  = (const float*)d_in[9];
  const float* bn1_v  = (const float*)d_in[10];
  const float* bn2_g  = (const float*)d_in[11];
  const float* bn2_b  = (const float*)d_in[12];
  const float* bn2_m  = (const float*)d_in[13];
  const float* bn2_v  = (const float*)d_in[14];
  const float* cgf_w  = (const float*)d_in[15];
  const float* cgf_b  = (const float*)d_in[16];
  const float* cgbn_g = (const float*)d_in[17];
  const float* cgbn_b = (const float*)d_in[18];
  const float* cgbn_m = (const float*)d_in[19];
  const float* cgbn_v = (const float*)d_in[20];
  const float* g1_w   = (const float*)d_in[21];
  const float* g1_b   = (const float*)d_in[22];
  const float* gbn_g  = (const float*)d_in[23];
  const float* gbn_b  = (const float*)d_in[24];
  const float* gbn_m  = (const float*)d_in[25];
  const float* gbn_v  = (const float*)d_in[26];
  const float* g2_w   = (const float*)d_in[27];
  const float* g2_b   = (const float*)d_in[28];
  const float* fc3_w  = (const float*)d_in[29];
  const float* fc3_b  = (const float*)d_in[30];

  char* w = (char*)d_ws;
  u16*   xn    = (u16*)  (w + 0);          // 39.3 MB, dead after GEMM1
  u16*   w1b   = (u16*)  (w + 39321600);
  u16*   c1t   = (u16*)  (w + 56098816);
  u16*   hb    = (u16*)  (w + 60293120);
  float* att   = (float*)(w + 138936320);
  float* act   = (float*)(w + 139243520);
  float* a_sum = (float*)(w + 158904320);
  float* vlad  = (float*)(w + 158912512);
  float* vladn = (float*)(w + 163106816);
  float* y     = (float*)(w + 167301120);
  float* z     = (float*)(w + 167563264);
  float* gate  = (float*)(w + 167596032);
  float* yg    = (float*)(w + 167858176);
  float* P     = (float*)(w + 0);          // split-K partials, reuses dead xn region (16.8 MB max)

  hipMemsetAsync(a_sum, 0, 32*64*sizeof(float), stream);
  k_l2norm<<<9600, 256, 0, stream>>>(x, xn);
  k_cvt<<<2048, 256, 0, stream>>>(fc1_w, w1b, (4096*2048)/4);
  k_transpose<<<dim3(128, 16), 256, 0, stream>>>(c1, c1t);
  // GEMM1: h = xn @ fc1_w.T + fc1_b  -> bf16 [9600][4096]
  k_gemm<false, true><<<dim3(75, 32), 256, 0, stream>>>(xn, w1b, fc1_b, nullptr, hb, 4096, 2048);
  k_att<<<9600, 256, 0, stream>>>(hb, fc2_w, fc2_b, att);
  // GEMM2: act = h @ c1 -> f32 [9600][512]
  k_gemm<true, false><<<dim3(75, 4), 256, 0, stream>>>(hb, c1t, nullptr, act, nullptr, 512, 4096);
  k_softmax<<<9600, 512, 0, stream>>>(act, att, bn1_g, bn1_b, bn1_m, bn1_v);
  k_asum<<<dim3(32, 8), 256, 0, stream>>>(act, a_sum);
  k_vlad<<<dim3(8, 32), 256, 0, stream>>>(hb, act, vlad);
  k_norm2<<<dim3(64, 32), 256, 0, stream>>>(vlad, a_sum, c2, bn2_g, bn2_b, bn2_m, bn2_v, vladn);

  // cgf: y = BN(vladn @ cgf_w.T + cgf_b)   N=2048, K=32768, KSPLIT=64, KC=512
  k_skgemm<<<dim3(16, 64), 256, 0, stream>>>(vladn, cgf_w, P, 2048, 32768, 512, 2048);
  k_skred<1><<<256, 256, 0, stream>>>(P, 64, 2048, 2048, cgf_b, cgbn_g, cgbn_b, cgbn_m, cgbn_v, y);
  // g1: z = relu(BN(y @ g1_w.T + g1_b))    N=256, K=2048, KSPLIT=32, KC=64
  k_skgemm<<<dim3(2, 32), 256, 0, stream>>>(y, g1_w, P, 256, 2048, 64, 256);
  k_skred<2><<<32, 256, 0, stream>>>(P, 32, 256, 256, g1_b, gbn_g, gbn_b, gbn_m, gbn_v, z);
  // g2: gate = sigmoid(z @ g2_w.T + g2_b)  N=2048, K=256, KSPLIT=4, KC=64
  k_skgemm<<<dim3(16, 4), 256, 0, stream>>>(z, g2_w, P, 2048, 256, 64, 2048);
  k_skred<3><<<256, 256, 0, stream>>>(P, 4, 2048, 2048, g2_b, nullptr, nullptr, nullptr, nullptr, gate);
  k_mul<<<256, 256, 0, stream>>>(y, gate, yg, 65536);
  // fc3: out = yg @ fc3_w.T + fc3_b        N=3862 (pad 3968), K=2048, KSPLIT=16, KC=128
  k_skgemm<<<dim3(31, 16), 256, 0, stream>>>(yg, fc3_w, P, 3862, 2048, 128, 3968);
  k_skred<0><<<483, 256, 0, stream>>>(P, 16, 3862, 3968, fc3_b, nullptr, nullptr, nullptr, nullptr, (float*)d_out);
}

// Round 3
// 1014.770 us; speedup vs baseline: 2.4762x; 1.2429x over previous
//
#include <hip/hip_runtime.h>

typedef unsigned short u16;
typedef unsigned int u32;
using f32x4 = __attribute__((ext_vector_type(4))) float;
using s16x8 = __attribute__((ext_vector_type(8))) short;
using u16x4 = __attribute__((ext_vector_type(4))) u16;

#define DEV __device__ __forceinline__

DEV float bf2f(u16 u) { union { u32 i; float f; } v; v.i = ((u32)u) << 16; return v.f; }
DEV u16 f2bf(float f) {
  union { float ff; u32 uu; } v; v.ff = f;
  u32 r = (v.uu + 0x7fffu + ((v.uu >> 16) & 1u)) >> 16;
  return (u16)r;
}

DEV void gl_lds16(const void* g, void* l) {
  __builtin_amdgcn_global_load_lds(
      (const __attribute__((address_space(1))) u32*)g,
      (__attribute__((address_space(3))) u32*)l, 16, 0, 0);
}

// ---------------- L2 normalize per frame, emit bf16 ----------------
__global__ __launch_bounds__(256) void k_l2norm(const float* __restrict__ x, u16* __restrict__ xn) {
  int r = blockIdx.x, t = threadIdx.x;
  const float* xr = x + (size_t)r * 2048;
  float v[8], s = 0.f;
#pragma unroll
  for (int i = 0; i < 8; i++) { v[i] = xr[t + i*256]; s += v[i]*v[i]; }
#pragma unroll
  for (int off = 32; off > 0; off >>= 1) s += __shfl_xor(s, off, 64);
  __shared__ float red[4];
  if ((t & 63) == 0) red[t >> 6] = s;
  __syncthreads();
  float inv = 1.f / fmaxf(sqrtf(red[0]+red[1]+red[2]+red[3]), 1e-12f);
  u16* xo = xn + (size_t)r * 2048;
#pragma unroll
  for (int i = 0; i < 8; i++) xo[t + i*256] = f2bf(v[i]*inv);
}

// ---------------- f32 -> bf16 ----------------
__global__ void k_cvt(const float* __restrict__ in, u16* __restrict__ out, int n4) {
  int i = blockIdx.x*256 + threadIdx.x, st = gridDim.x*256;
  for (; i < n4; i += st) {
    f32x4 v = ((const f32x4*)in)[i];
    u16x4 o;
    o[0] = f2bf(v[0]); o[1] = f2bf(v[1]); o[2] = f2bf(v[2]); o[3] = f2bf(v[3]);
    ((u16x4*)out)[i] = o;
  }
}

// ---------------- c1 [4096][512] -> c1ext bf16 rows 0..511 [640][4096] ----------------
__global__ __launch_bounds__(256) void k_transpose(const float* __restrict__ c1, u16* __restrict__ c1t) {
  __shared__ float tile[32][33];
  int k0 = blockIdx.x*32, n0 = blockIdx.y*32;
  int tx = threadIdx.x & 31, ty = threadIdx.x >> 5;
  for (int i = ty; i < 32; i += 8) tile[i][tx] = c1[(size_t)(k0+i)*512 + n0 + tx];
  __syncthreads();
  for (int i = ty; i < 32; i += 8) c1t[(size_t)(n0+i)*4096 + k0 + tx] = f2bf(tile[tx][i]);
}

// ---------------- bf16 MFMA NT GEMM with XOR-swizzled LDS + supertile remap ----------------
// C[m,n] = sum_k A[m,k]*Bt[n,k] (+bias). 128x128 tile, BK=32.
template<bool WF32, bool WBF16>
__global__ __launch_bounds__(256) void k_gemm(
    const u16* __restrict__ A, const u16* __restrict__ Bt, const float* __restrict__ bias,
    float* __restrict__ Cf, u16* __restrict__ Cb, int N, int K, int Nlim,
    int MT, int NT, int swz) {
  __shared__ u16 As[128*32];
  __shared__ u16 Bs[128*32];
  int bid = blockIdx.x, mt, nt;
  if (swz) {
    int mg = (MT + 7) >> 3;
    int gid = bid >> 5, gl = bid & 31;
    mt = (gid % mg)*8 + (gl & 7);
    nt = (gid / mg)*4 + (gl >> 3);
    if (mt >= MT) return;
  } else { mt = bid % MT; nt = bid / MT; }
  int t = threadIdx.x, wv = t >> 6;
  int quad = (t & 63) >> 4, lr = t & 15;
  size_t m0 = (size_t)mt * 128, n0 = (size_t)nt * 128;
  int wm = wv & 1, wn = wv >> 1;
  int srow = t >> 2;
  int scol = (((t & 3) ^ ((t >> 3) & 3)) * 8);   // XOR-swizzled k-chunk
  const u16* gA = A + (m0 + srow)*(size_t)K + scol;
  const u16* gB = Bt + (n0 + srow)*(size_t)K + scol;
  u16* lA = &As[wv*512];
  u16* lB = &Bs[wv*512];
  int xq = (quad ^ ((lr >> 1) & 3)) * 8;          // matching frag-read chunk
  f32x4 acc[4][4];
#pragma unroll
  for (int i = 0; i < 4; i++)
#pragma unroll
    for (int j = 0; j < 4; j++) acc[i][j] = (f32x4){0.f,0.f,0.f,0.f};
  for (int k0 = 0; k0 < K; k0 += 32) {
    gl_lds16(gA + k0, lA);
    gl_lds16(gA + (size_t)64*K + k0, lA + 2048);
    gl_lds16(gB + k0, lB);
    gl_lds16(gB + (size_t)64*K + k0, lB + 2048);
    __syncthreads();
    s16x8 af[4], bfr[4];
#pragma unroll
    for (int i = 0; i < 4; i++) {
      af[i]  = *(const s16x8*)&As[(wm*64 + i*16 + lr)*32 + xq];
      bfr[i] = *(const s16x8*)&Bs[(wn*64 + i*16 + lr)*32 + xq];
    }
#pragma unroll
    for (int i = 0; i < 4; i++)
#pragma unroll
      for (int j = 0; j < 4; j++)
        acc[i][j] = __builtin_amdgcn_mfma_f32_16x16x32_bf16(af[i], bfr[j], acc[i][j], 0, 0, 0);
    __syncthreads();
  }
#pragma unroll
  for (int j = 0; j < 4; j++) {
    size_t nn = n0 + wn*64 + j*16 + lr;
    if ((int)nn >= Nlim) continue;
    float bj = bias ? bias[nn] : 0.f;
#pragma unroll
    for (int i = 0; i < 4; i++) {
      size_t mr = m0 + wm*64 + i*16 + quad*4;
#pragma unroll
      for (int r = 0; r < 4; r++) {
        float v = acc[i][j][r] + bj;
        if (WF32)  Cf[(mr + r)*N + nn] = v;
        if (WBF16) Cb[(mr + r)*N + nn] = f2bf(v);
      }
    }
  }
}

// ---------------- hb [9600][4096] -> hbT [32][512][2400] (bf16) ----------------
// hbT[b][f][n] = hb[b*300 + n/8][(n%8)*512 + f]
__global__ __launch_bounds__(256) void k_hbt(const u16* __restrict__ hb, u16* __restrict__ hbT) {
  __shared__ u16 tile[64*33];
  int nt = blockIdx.x, ft = blockIdx.y, b = blockIdx.z, t = threadIdx.x;
  int n0 = nt*32, f0 = ft*64;
  int rrel = t >> 6, g = (t >> 3) & 7, fi = (t & 7)*8;
  const u16* src = hb + ((size_t)(b*300 + (n0 >> 3) + rrel))*4096 + g*512 + f0 + fi;
  u16 v[8];
  *(u16x4*)v = *(const u16x4*)src;
  *(u16x4*)(v+4) = *(const u16x4*)(src+4);
  int nl = rrel*8 + g;
#pragma unroll
  for (int e = 0; e < 8; e++) tile[(fi+e)*33 + nl] = v[e];
  __syncthreads();
  int f = t >> 2, nc = (t & 3)*8;
  u16 o[8];
#pragma unroll
  for (int e = 0; e < 8; e++) o[e] = tile[f*33 + nc + e];
  u16* dst = hbT + ((size_t)b*512 + f0 + f)*2400 + n0 + nc;
  *(u16x4*)dst = *(u16x4*)o;
  *(u16x4*)(dst+4) = *(u16x4*)(o+4);
}

// ---------------- bn1 + softmax(K=64) + att(from ext cols) -> actT bf16 [32][64][2400] ----------------
__global__ __launch_bounds__(512) void k_softmax(const float* __restrict__ act_ext,
    const float* __restrict__ fc2_b,
    const float* __restrict__ g, const float* __restrict__ b,
    const float* __restrict__ mu, const float* __restrict__ var, u16* __restrict__ actT) {
  int m = blockIdx.x, t = threadIdx.x;
  int bb = m / 300, fr = m - bb*300;
  int gi = t >> 6, k = t & 63, c = t;
  float v = act_ext[(size_t)m*640 + c];
  v = (v - mu[c]) * rsqrtf(var[c] + 1e-5f) * g[c] + b[c];
  float mx = v;
#pragma unroll
  for (int off = 32; off > 0; off >>= 1) mx = fmaxf(mx, __shfl_xor(mx, off, 64));
  float e = __expf(v - mx);
  float s = e;
#pragma unroll
  for (int off = 32; off > 0; off >>= 1) s += __shfl_xor(s, off, 64);
  float attl = act_ext[(size_t)m*640 + 512 + gi] + fc2_b[gi];
  float attv = 1.f / (1.f + __expf(-attl));
  float r = (e / s) * attv;
  __shared__ u16 st[64*9];
  st[k*9 + gi] = f2bf(r);
  __syncthreads();
  if (t < 64) {
    u16 o[8];
#pragma unroll
    for (int e2 = 0; e2 < 8; e2++) o[e2] = st[t*9 + e2];
    u16* dst = actT + ((size_t)bb*64 + t)*2400 + fr*8;
    *(u16x4*)dst = *(u16x4*)o;
    *(u16x4*)(dst+4) = *(u16x4*)(o+4);
  }
}

// ---------------- a_sum[b,k] = sum_n actT[b,k,n] ----------------
__global__ __launch_bounds__(256) void k_asum(const u16* __restrict__ actT, float* __restrict__ a_sum) {
  int b = blockIdx.x, t = threadIdx.x;
  int k = t >> 2, q = t & 3;
  const u16* p = actT + ((size_t)b*64 + k)*2400 + q*600;
  float acc = 0.f;
  for (int j = 0; j < 600; j += 8) {
    u16x4 a0 = *(const u16x4*)(p + j);
    u16x4 a1 = *(const u16x4*)(p + j + 4);
    acc += bf2f(a0[0])+bf2f(a0[1])+bf2f(a0[2])+bf2f(a0[3])
         + bf2f(a1[0])+bf2f(a1[1])+bf2f(a1[2])+bf2f(a1[3]);
  }
  __shared__ float red[256];
  red[t] = acc;
  __syncthreads();
  if (t < 64) a_sum[b*64 + t] = red[t*4] + red[t*4+1] + red[t*4+2] + red[t*4+3];
}

// ---------------- vlad MFMA: P2[ns][b][f][k] = sum_{n in chunk} hbT[b][f][n]*actT[b][k][n] ----------------
// grid (ft=4, b=32, ns=5), block 256; tile 128f x 64k, n-chunk 480 (15 x BK=32)
__global__ __launch_bounds__(256) void k_vlad(const u16* __restrict__ hbT, const u16* __restrict__ actT,
                                              float* __restrict__ P2) {
  __shared__ u16 As[128*32];
  __shared__ u16 Bs[64*32];
  int t = threadIdx.x, wv = t >> 6;
  int quad = (t & 63) >> 4, lr = t & 15;
  int ft = blockIdx.x, b = blockIdx.y, ns = blockIdx.z;
  int wm = wv & 1, wn = wv >> 1;
  int srow = t >> 2;
  int scol = (((t & 3) ^ ((t >> 3) & 3)) * 8);
  int xq = (quad ^ ((lr >> 1) & 3)) * 8;
  const u16* gA = hbT + ((size_t)b*512 + ft*128 + srow)*2400 + ns*480 + scol;
  const u16* gB = actT + ((size_t)b*64 + srow)*2400 + ns*480 + scol;
  u16* lA = &As[wv*512];
  u16* lB = &Bs[wv*512];
  f32x4 acc[4][2];
#pragma unroll
  for (int i = 0; i < 4; i++)
#pragma unroll
    for (int j = 0; j < 2; j++) acc[i][j] = (f32x4){0.f,0.f,0.f,0.f};
  for (int k0 = 0; k0 < 480; k0 += 32) {
    gl_lds16(gA + k0, lA);
    gl_lds16(gA + (size_t)64*2400 + k0, lA + 2048);
    gl_lds16(gB + k0, lB);
    __syncthreads();
    s16x8 af[4], bfr[2];
#pragma unroll
    for (int i = 0; i < 4; i++)
      af[i] = *(const s16x8*)&As[(wm*64 + i*16 + lr)*32 + xq];
#pragma unroll
    for (int j = 0; j < 2; j++)
      bfr[j] = *(const s16x8*)&Bs[(wn*32 + j*16 + lr)*32 + xq];
#pragma unroll
    for (int i = 0; i < 4; i++)
#pragma unroll
      for (int j = 0; j < 2; j++)
        acc[i][j] = __builtin_amdgcn_mfma_f32_16x16x32_bf16(af[i], bfr[j], acc[i][j], 0, 0, 0);
    __syncthreads();
  }
  size_t base = ((size_t)ns*32 + b)*512*64;
#pragma unroll
  for (int j = 0; j < 2; j++) {
    int kc = wn*32 + j*16 + lr;
#pragma unroll
    for (int i = 0; i < 4; i++) {
      int f = ft*128 + wm*64 + i*16 + quad*4;
#pragma unroll
      for (int r = 0; r < 4; r++)
        P2[base + (size_t)(f + r)*64 + kc] = acc[i][j][r];
    }
  }
}

// ---------------- sum partials, subtract a, intra-norm over f, bn2 -> vladn [32][32768] ----------------
__global__ __launch_bounds__(256) void k_norm2(const float* __restrict__ P2, const float* __restrict__ a_sum,
    const float* __restrict__ c2, const float* __restrict__ g, const float* __restrict__ b,
    const float* __restrict__ mu, const float* __restrict__ var, float* __restrict__ out) {
  int k = blockIdx.x, bb = blockIdx.y, t = threadIdx.x;
  float as = a_sum[bb*64 + k];
  int f0 = t, f1 = t + 256;
  const size_t PS = (size_t)32*512*64;
  size_t base = (size_t)bb*512*64;
  float x0 = 0.f, x1 = 0.f;
#pragma unroll
  for (int ns = 0; ns < 5; ns++) {
    x0 += P2[ns*PS + base + (size_t)f0*64 + k];
    x1 += P2[ns*PS + base + (size_t)f1*64 + k];
  }
  x0 -= as * c2[f0*64 + k];
  x1 -= as * c2[f1*64 + k];
  float s = x0*x0 + x1*x1;
#pragma unroll
  for (int off = 32; off > 0; off >>= 1) s += __shfl_xor(s, off, 64);
  __shared__ float red[4];
  if ((t & 63) == 0) red[t >> 6] = s;
  __syncthreads();
  float inv = 1.f / fmaxf(sqrtf(red[0]+red[1]+red[2]+red[3]), 1e-12f);
  int c0 = f0*64 + k, c1 = f1*64 + k;
  out[(size_t)bb*32768 + c0] = (x0*inv - mu[c0]) * rsqrtf(var[c0]+1e-5f) * g[c0] + b[c0];
  out[(size_t)bb*32768 + c1] = (x1*inv - mu[c1]) * rsqrtf(var[c1]+1e-5f) * g[c1] + b[c1];
}

// ---------------- split-K small-M MFMA GEMM ----------------
__global__ __launch_bounds__(256) void k_skgemm(
    const float* __restrict__ A, const float* __restrict__ W,
    float* __restrict__ P, int N, int K, int KC, int Npad) {
  constexpr int LDB = 72;
  __shared__ u16 Bs[128*LDB];
  __shared__ u16 As[32*LDB];
  int t = threadIdx.x;
  int wv = t >> 6, quad = (t & 63) >> 4, lr = t & 15;
  int n0 = blockIdx.x * 128;
  size_t kc0 = (size_t)blockIdx.y * KC;
  f32x4 acc[2][2];
#pragma unroll
  for (int i = 0; i < 2; i++)
#pragma unroll
    for (int j = 0; j < 2; j++) acc[i][j] = (f32x4){0.f,0.f,0.f,0.f};
  int wl[8]; size_t wg[8];
#pragma unroll
  for (int i = 0; i < 8; i++) {
    int slot = i*256 + t;
    int r = slot >> 4, q = slot & 15;
    int row = n0 + r; if (row >= N) row = N - 1;
    wl[i] = r*LDB + q*4;
    wg[i] = (size_t)row*K + kc0 + q*4;
  }
  int al[2]; size_t ag[2];
#pragma unroll
  for (int i = 0; i < 2; i++) {
    int slot = i*256 + t;
    int r = slot >> 4, q = slot & 15;
    al[i] = r*LDB + q*4;
    ag[i] = (size_t)r*K + kc0 + q*4;
  }
  int nst = KC >> 6;
  f32x4 wv4[8], av4[2];
#pragma unroll
  for (int i = 0; i < 8; i++) wv4[i] = *(const f32x4*)(W + wg[i]);
#pragma unroll
  for (int i = 0; i < 2; i++) av4[i] = *(const f32x4*)(A + ag[i]);
  for (int s = 0; s < nst; s++) {
    if (s) __syncthreads();
#pragma unroll
    for (int i = 0; i < 8; i++) {
      u16x4 o;
      o[0] = f2bf(wv4[i][0]); o[1] = f2bf(wv4[i][1]);
      o[2] = f2bf(wv4[i][2]); o[3] = f2bf(wv4[i][3]);
      *(u16x4*)&Bs[wl[i]] = o;
    }
#pragma unroll
    for (int i = 0; i < 2; i++) {
      u16x4 o;
      o[0] = f2bf(av4[i][0]); o[1] = f2bf(av4[i][1]);
      o[2] = f2bf(av4[i][2]); o[3] = f2bf(av4[i][3]);
      *(u16x4*)&As[al[i]] = o;
    }
    __syncthreads();
    if (s + 1 < nst) {
      int off = (s + 1) * 64;
#pragma unroll
      for (int i = 0; i < 8; i++) wv4[i] = *(const f32x4*)(W + wg[i] + off);
#pragma unroll
      for (int i = 0; i < 2; i++) av4[i] = *(const f32x4*)(A + ag[i] + off);
    }
#pragma unroll
    for (int ks = 0; ks < 2; ks++) {
      s16x8 af[2];
#pragma unroll
      for (int i = 0; i < 2; i++)
        af[i] = *(const s16x8*)&As[(i*16 + lr)*LDB + ks*32 + quad*8];
#pragma unroll
      for (int j = 0; j < 2; j++) {
        s16x8 bf = *(const s16x8*)&Bs[(wv*32 + j*16 + lr)*LDB + ks*32 + quad*8];
#pragma unroll
        for (int i = 0; i < 2; i++)
          acc[i][j] = __builtin_amdgcn_mfma_f32_16x16x32_bf16(af[i], bf, acc[i][j], 0, 0, 0);
      }
    }
  }
#pragma unroll
  for (int i = 0; i < 2; i++)
#pragma unroll
    for (int j = 0; j < 2; j++) {
      int n = n0 + wv*32 + j*16 + lr;
#pragma unroll
      for (int r = 0; r < 4; r++) {
        int m = i*16 + quad*4 + r;
        P[((size_t)blockIdx.y*32 + m)*Npad + n] = acc[i][j][r];
      }
    }
}

// ---------------- split-K reduce + epilogue ----------------
template<int EPI>
__global__ __launch_bounds__(256) void k_skred(const float* __restrict__ P, int KSPLIT, int N, int Npad,
    const float* __restrict__ bias, const float* __restrict__ bg, const float* __restrict__ bb,
    const float* __restrict__ bm, const float* __restrict__ bv, float* __restrict__ C) {
  int idx = blockIdx.x*256 + threadIdx.x;
  if (idx >= 32*N) return;
  int m = idx / N, n = idx - m*N;
  float s = 0.f;
  for (int k = 0; k < KSPLIT; k++) s += P[((size_t)k*32 + m)*Npad + n];
  float v = s + (bias ? bias[n] : 0.f);
  if (EPI == 1 || EPI == 2) {
    v = (v - bm[n]) * rsqrtf(bv[n] + 1e-5f) * bg[n] + bb[n];
    if (EPI == 2) v = fmaxf(v, 0.f);
  } else if (EPI == 3) {
    v = 1.f / (1.f + __expf(-v));
  }
  C[idx] = v;
}

// ---------------- elementwise multiply ----------------
__global__ void k_mul(const float* __restrict__ a, const float* __restrict__ b, float* __restrict__ o, int n) {
  int i = blockIdx.x*256 + threadIdx.x;
  if (i < n) o[i] = a[i]*b[i];
}

extern "C" void kernel_launch(void* const* d_in, const int* in_sizes, int n_in,
                              void* d_out, int out_size, void* d_ws, size_t ws_size,
                              hipStream_t stream) {
  (void)in_sizes; (void)n_in; (void)out_size; (void)ws_size;
  const float* x      = (const float*)d_in[0];
  const float* fc1_w  = (const float*)d_in[1];
  const float* fc1_b  = (const float*)d_in[2];
  const float* fc2_w  = (const float*)d_in[3];
  const float* fc2_b  = (const float*)d_in[4];
  const float* c1     = (const float*)d_in[5];
  const float* c2     = (const float*)d_in[6];
  const float* bn1_g  = (const float*)d_in[7];
  const float* bn1_b  = (const float*)d_in[8];
  const float* bn1_m  = (const float*)d_in[9];
  const float* bn1_v  = (const float*)d_in[10];
  const float* bn2_g  = (const float*)d_in[11];
  const float* bn2_b  = (const float*)d_in[12];
  const float* bn2_m  = (const float*)d_in[13];
  const float* bn2_v  = (const float*)d_in[14];
  const float* cgf_w  = (const float*)d_in[15];
  const float* cgf_b  = (const float*)d_in[16];
  const float* cgbn_g = (const float*)d_in[17];
  const float* cgbn_b = (const float*)d_in[18];
  const float* cgbn_m = (const float*)d_in[19];
  const float* cgbn_v = (const float*)d_in[20];
  const float* g1_w   = (const float*)d_in[21];
  const float* g1_b   = (const float*)d_in[22];
  const float* gbn_g  = (const float*)d_in[23];
  const float* gbn_b  = (const float*)d_in[24];
  const float* gbn_m  = (const float*)d_in[25];
  const float* gbn_v  = (const float*)d_in[26];
  const float* g2_w   = (const float*)d_in[27];
  const float* g2_b   = (const float*)d_in[28];
  const float* fc3_w  = (const float*)d_in[29];
  const float* fc3_b  = (const float*)d_in[30];

  char* w = (char*)d_ws;
  // region [0, 78643200): xn + w1b during phase 1; hbT after GEMM1
  u16*   xn    = (u16*)  (w + 0);                 // 39,321,600
  u16*   w1b   = (u16*)  (w + 39321600);          // 16,777,216
  u16*   hbT   = (u16*)  (w + 0);                 // 78,643,200 (after GEMM1)
  u16*   hb    = (u16*)  (w + 78643200);          // 78,643,200
  u16*   c1ext = (u16*)  (w + 157286400);         // 640*4096*2 = 5,242,880
  float* actx  = (float*)(w + 162529280);         // 9600*640*4 = 24,576,000
  u16*   actT  = (u16*)  (w + 187105280);         // 32*64*2400*2 = 9,830,400
  float* P2    = (float*)(w + 196935680);         // 5*32*512*64*4 = 20,971,520
  float* P     = (float*)(w + 196935680);         // skgemm partials reuse P2 region
  float* a_sum = (float*)(w + 217907200);         // 8,192
  float* vladn = (float*)(w + 217915392);         // 4,194,304
  float* y     = (float*)(w + 222109696);         // 262,144
  float* z     = (float*)(w + 222371840);         // 32,768
  float* gate  = (float*)(w + 222404608);         // 262,144
  float* yg    = (float*)(w + 222666752);         // 262,144
  // total ~222.9 MB

  k_l2norm<<<9600, 256, 0, stream>>>(x, xn);
  k_cvt<<<2048, 256, 0, stream>>>(fc1_w, w1b, (4096*2048)/4);
  k_transpose<<<dim3(128, 16), 256, 0, stream>>>(c1, c1ext);
  k_cvt<<<32, 256, 0, stream>>>(fc2_w, c1ext + (size_t)512*4096, (8*4096)/4);
  // GEMM1: h = xn @ fc1_w.T + fc1_b -> bf16 [9600][4096]; supertile swizzle, grid 80 groups * 32
  k_gemm<false, true><<<2560, 256, 0, stream>>>(xn, w1b, fc1_b, nullptr, hb, 4096, 2048, 4096, 75, 32, 1);
  // hb -> hbT [32][512][2400] (overwrites xn/w1b)
  k_hbt<<<dim3(75, 8, 32), 256, 0, stream>>>(hb, hbT);
  // GEMM2+att: act_ext = h @ [c1 | fc2_w].T -> f32 [9600][640] (store cols < 520)
  k_gemm<true, false><<<375, 256, 0, stream>>>(hb, c1ext, nullptr, actx, nullptr, 640, 4096, 520, 75, 5, 0);
  // bn1 + softmax + att -> actT bf16 [32][64][2400]
  k_softmax<<<9600, 512, 0, stream>>>(actx, fc2_b, bn1_g, bn1_b, bn1_m, bn1_v, actT);
  k_asum<<<32, 256, 0, stream>>>(actT, a_sum);
  // vlad partials
  k_vlad<<<dim3(4, 32, 5), 256, 0, stream>>>(hbT, actT, P2);
  k_norm2<<<dim3(64, 32), 256, 0, stream>>>(P2, a_sum, c2, bn2_g, bn2_b, bn2_m, bn2_v, vladn);

  // cgf: y = BN(vladn @ cgf_w.T + cgf_b)   N=2048, K=32768, KSPLIT=64, KC=512
  k_skgemm<<<dim3(16, 64), 256, 0, stream>>>(vladn, cgf_w, P, 2048, 32768, 512, 2048);
  k_skred<1><<<256, 256, 0, stream>>>(P, 64, 2048, 2048, cgf_b, cgbn_g, cgbn_b, cgbn_m, cgbn_v, y);
  // g1: z = relu(BN(y @ g1_w.T + g1_b))    N=256, K=2048, KSPLIT=32, KC=64
  k_skgemm<<<dim3(2, 32), 256, 0, stream>>>(y, g1_w, P, 256, 2048, 64, 256);
  k_skred<2><<<32, 256, 0, stream>>>(P, 32, 256, 256, g1_b, gbn_g, gbn_b, gbn_m, gbn_v, z);
  // g2: gate = sigmoid(z @ g2_w.T + g2_b)  N=2048, K=256, KSPLIT=4, KC=64
  k_skgemm<<<dim3(16, 4), 256, 0, stream>>>(z, g2_w, P, 2048, 256, 64, 2048);
  k_skred<3><<<256, 256, 0, stream>>>(P, 4, 2048, 2048, g2_b, nullptr, nullptr, nullptr, nullptr, gate);
  k_mul<<<256, 256, 0, stream>>>(y, gate, yg, 65536);
  // fc3: out = yg @ fc3_w.T + fc3_b        N=3862 (pad 3968), K=2048, KSPLIT=16, KC=128
  k_skgemm<<<dim3(31, 16), 256, 0, stream>>>(yg, fc3_w, P, 3862, 2048, 128, 3968);
  k_skred<0><<<483, 256, 0, stream>>>(P, 16, 3862, 3968, fc3_b, nullptr, nullptr, nullptr, nullptr, (float*)d_out);
}